// Round 1
// baseline (1892.647 us; speedup 1.0000x reference)
//
#include <hip/hip_runtime.h>

typedef __bf16 bf16x8 __attribute__((ext_vector_type(8)));
typedef float f32x4 __attribute__((ext_vector_type(4)));
typedef unsigned short ushort_t;
typedef unsigned short u16x8 __attribute__((ext_vector_type(8)));

#define BSZ 4096
#define HID 1024
#define INPD 512
#define NSPAN 8
#define NOUT 2
#define NDAYS 20
#define XLD 1536  // X = [inp(512) | h(1024)] leading dim

__device__ __forceinline__ ushort_t f2bf(float f) {
  union { float f; unsigned u; } v; v.f = f;
  unsigned r = v.u + 0x7FFFu + ((v.u >> 16) & 1u);
  return (ushort_t)(r >> 16);
}
__device__ __forceinline__ float bf2f(ushort_t b) {
  union { unsigned u; float f; } v; v.u = ((unsigned)b) << 16;
  return v.f;
}
__device__ __forceinline__ float sigf(float x) { return 1.f / (1.f + __expf(-x)); }
__device__ __forceinline__ float tanhfast(float x) { return 2.f / (1.f + __expf(-2.f * x)) - 1.f; }

// ---------------------------------------------------------------------------
// Weight prep: Wg[r][c] bf16, r = (j/16)*64 + gate*16 + (j%16), c = [W_ih | W_hh]
// so a 64-wide N-group holds gates i,f,g,o for 16 consecutive hidden units.
// bg[r] = b_ih[src] + b_hh[src] (same reorder).
// ---------------------------------------------------------------------------
__global__ void prep_gates_w(const float* __restrict__ Wih, const float* __restrict__ Whh,
                             const float* __restrict__ bih, const float* __restrict__ bhh,
                             ushort_t* __restrict__ Wg, float* __restrict__ bg) {
  int gid = blockIdx.x * 256 + threadIdx.x;  // over 4096*1536
  int r = gid / XLD;
  int cc = gid - r * XLD;
  int g = (r >> 4) & 3;
  int j = (r >> 6) * 16 + (r & 15);
  int src = g * HID + j;
  float v = (cc < INPD) ? Wih[(size_t)src * INPD + cc] : Whh[(size_t)src * HID + (cc - INPD)];
  Wg[gid] = f2bf(v);
  if (cc == 0) bg[r] = bih[src] + bhh[src];
}

__global__ void prep_fcin_w(const float* __restrict__ W, ushort_t* __restrict__ Wo) {
  int gid = blockIdx.x * 256 + threadIdx.x;  // over 512*1024
  Wo[gid] = f2bf(W[gid]);
}

// X_A = [0 | bf16(hx)], c = cx
__global__ void init_kernel(const float* __restrict__ hx, const float* __restrict__ cx,
                            ushort_t* __restrict__ X, float* __restrict__ c) {
  int gid = blockIdx.x * 256 + threadIdx.x;  // over 4096*1024
  int b = gid >> 10, j = gid & 1023;
  X[(size_t)b * XLD + INPD + j] = f2bf(hx[gid]);
  if (j < INPD) X[(size_t)b * XLD + j] = 0;
  c[gid] = cx[gid];
}

// num_spans = softmax(hx @ W_span.T + b_span), fp32 exact-ish
__global__ void span_kernel(const float* __restrict__ hx, const float* __restrict__ Wspan,
                            const float* __restrict__ bspan, float* __restrict__ out) {
  int gid = blockIdx.x * 256 + threadIdx.x;  // over 4096*8
  int b = gid >> 3, o = gid & 7;
  const float4* hr = (const float4*)(hx + (size_t)b * HID);
  const float4* wr = (const float4*)(Wspan + (size_t)o * HID);
  float acc = 0.f;
  for (int i = 0; i < HID / 4; ++i) {
    float4 h = hr[i], w = wr[i];
    acc += h.x * w.x + h.y * w.y + h.z * w.z + h.w * w.w;
  }
  acc += bspan[o];
  float m = acc;
  for (int s = 1; s < 8; s <<= 1) m = fmaxf(m, __shfl_xor(m, s));
  float e = __expf(acc - m);
  float ssum = e;
  for (int s = 1; s < 8; s <<= 1) ssum += __shfl_xor(ssum, s);
  out[gid] = e / ssum;
}

// out[b][t][:] = softmax(h_b @ W_fcout.T + b_fcout); one wave per row
__global__ void fcout_kernel(const ushort_t* __restrict__ X, const float* __restrict__ W,
                             const float* __restrict__ bvec, float* __restrict__ outp, int t) {
  const int lane = threadIdx.x & 63;
  const int wave = threadIdx.x >> 6;
  const int b = blockIdx.x * 4 + wave;
  const ushort_t* h = X + (size_t)b * XLD + INPD + lane * 16;
  u16x8 h0 = *(const u16x8*)(h);
  u16x8 h1 = *(const u16x8*)(h + 8);
  const float* w0 = W + lane * 16;
  const float* w1 = W + HID + lane * 16;
  float l0 = 0.f, l1 = 0.f;
#pragma unroll
  for (int j = 0; j < 8; ++j) {
    float ha = bf2f(h0[j]);
    l0 += ha * w0[j];
    l1 += ha * w1[j];
    float hb = bf2f(h1[j]);
    l0 += hb * w0[j + 8];
    l1 += hb * w1[j + 8];
  }
#pragma unroll
  for (int s = 32; s > 0; s >>= 1) {
    l0 += __shfl_xor(l0, s);
    l1 += __shfl_xor(l1, s);
  }
  if (lane == 0) {
    l0 += bvec[0];
    l1 += bvec[1];
    float m = fmaxf(l0, l1);
    float e0 = __expf(l0 - m), e1 = __expf(l1 - m);
    float inv = 1.f / (e0 + e1);
    float* o = outp + (size_t)b * (NDAYS * NOUT) + t * NOUT;
    o[0] = e0 * inv;
    o[1] = e1 * inv;
  }
}

// ---------------------------------------------------------------------------
// GEMM: C[m][n] = sum_k A[m][k]*B[n][k]  (both row-major [rows][K] bf16)
// 128x128 tile, BK=32, 4 waves, each wave 64x64 via 4x4 mfma_f32_16x16x32_bf16.
// EPI=0: fused LSTM cell epilogue (B = reordered gate weights).
// EPI=1: relu+bias, bf16 store to hout col n (fcin).
// ---------------------------------------------------------------------------
template <int EPI>
__global__ void gemm_kernel(const ushort_t* __restrict__ A, int lda,
                            const ushort_t* __restrict__ B, int ldb, int K,
                            const float* __restrict__ bias, float* __restrict__ cbuf,
                            ushort_t* __restrict__ hout) {
  __shared__ __align__(16) ushort_t ldsA[128 * 32];
  __shared__ __align__(16) ushort_t ldsB[128 * 32];
  const int tid = threadIdx.x;
  const int lane = tid & 63;
  const int wave = tid >> 6;

  // XCD-aware bijective swizzle (nwg % 8 == 0 for both grids used)
  int bid = blockIdx.y * gridDim.x + blockIdx.x;
  int nwg = gridDim.x * gridDim.y;
  int cpx = nwg >> 3;
  int swz = (bid & 7) * cpx + (bid >> 3);
  int bx = swz % gridDim.x;
  int by = swz / gridDim.x;
  const int bm = bx * 128;
  const int bn = by * 128;
  const int wm = (wave >> 1) * 64;
  const int wn = (wave & 1) * 64;

  f32x4 acc[4][4] = {};

  // staging: slot = row*4 + kpart (8 bf16 per slot); 2 slots/thread/tile
  const int s0 = tid, s1 = tid + 256;
  const int r0 = s0 >> 2, kp0 = s0 & 3;
  const int r1 = s1 >> 2, kp1 = s1 & 3;
  const ushort_t* gA0 = A + (size_t)(bm + r0) * lda + kp0 * 8;
  const ushort_t* gA1 = A + (size_t)(bm + r1) * lda + kp1 * 8;
  const ushort_t* gB0 = B + (size_t)(bn + r0) * ldb + kp0 * 8;
  const ushort_t* gB1 = B + (size_t)(bn + r1) * ldb + kp1 * 8;
  // swizzled LDS slot within row: kp ^ (row & 3)
  const int wA0 = (r0 * 4 + (kp0 ^ (r0 & 3))) * 8;
  const int wA1 = (r1 * 4 + (kp1 ^ (r1 & 3))) * 8;

  u16x8 a0 = *(const u16x8*)(gA0);
  u16x8 a1 = *(const u16x8*)(gA1);
  u16x8 b0 = *(const u16x8*)(gB0);
  u16x8 b1 = *(const u16x8*)(gB1);

  for (int k0 = 0; k0 < K; k0 += 32) {
    __syncthreads();  // prior iter's frag reads done
    *(u16x8*)(ldsA + wA0) = a0;
    *(u16x8*)(ldsA + wA1) = a1;
    *(u16x8*)(ldsB + wA0) = b0;
    *(u16x8*)(ldsB + wA1) = b1;
    __syncthreads();
    if (k0 + 32 < K) {  // prefetch next K-tile into regs (overlaps MFMA)
      a0 = *(const u16x8*)(gA0 + k0 + 32);
      a1 = *(const u16x8*)(gA1 + k0 + 32);
      b0 = *(const u16x8*)(gB0 + k0 + 32);
      b1 = *(const u16x8*)(gB1 + k0 + 32);
    }
    bf16x8 af[4], bf[4];
    const int q = lane >> 4;
#pragma unroll
    for (int i = 0; i < 4; ++i) {
      int ar = wm + i * 16 + (lane & 15);
      af[i] = *(const bf16x8*)(ldsA + (ar * 4 + (q ^ (ar & 3))) * 8);
      int br = wn + i * 16 + (lane & 15);
      bf[i] = *(const bf16x8*)(ldsB + (br * 4 + (q ^ (br & 3))) * 8);
    }
#pragma unroll
    for (int mi = 0; mi < 4; ++mi)
#pragma unroll
      for (int ni = 0; ni < 4; ++ni)
        acc[mi][ni] = __builtin_amdgcn_mfma_f32_16x16x32_bf16(af[mi], bf[ni], acc[mi][ni], 0, 0, 0);
  }

  if (EPI == 0) {
    // 64-col group = gates i,f,g,o for 16 hidden units; lane&15 picks the unit
    const int colbase = bn + wn;  // multiple of 64
    const int jj = (colbase >> 6) * 16 + (lane & 15);
    const int cb = colbase + (lane & 15);
    const float bI = bias[cb];
    const float bF = bias[cb + 16];
    const float bG = bias[cb + 32];
    const float bO = bias[cb + 48];
#pragma unroll
    for (int mi = 0; mi < 4; ++mi) {
#pragma unroll
      for (int r = 0; r < 4; ++r) {
        const int b = bm + wm + mi * 16 + ((lane >> 4) << 2) + r;
        float ig = sigf(acc[mi][0][r] + bI);
        float fg = sigf(acc[mi][1][r] + bF);
        float gg = tanhfast(acc[mi][2][r] + bG);
        float og = sigf(acc[mi][3][r] + bO);
        size_t cidx = (size_t)b * HID + jj;
        float cn = fg * cbuf[cidx] + ig * gg;
        cbuf[cidx] = cn;
        hout[(size_t)b * XLD + INPD + jj] = f2bf(og * tanhfast(cn));
      }
    }
  } else {
#pragma unroll
    for (int mi = 0; mi < 4; ++mi) {
#pragma unroll
      for (int ni = 0; ni < 4; ++ni) {
        const int n = bn + wn + ni * 16 + (lane & 15);
        const float bb = bias[n];
#pragma unroll
        for (int r = 0; r < 4; ++r) {
          const int b = bm + wm + mi * 16 + ((lane >> 4) << 2) + r;
          float v = fmaxf(acc[mi][ni][r] + bb, 0.f);
          hout[(size_t)b * XLD + n] = f2bf(v);
        }
      }
    }
  }
}

extern "C" void kernel_launch(void* const* d_in, const int* in_sizes, int n_in, void* d_out,
                              int out_size, void* d_ws, size_t ws_size, hipStream_t stream) {
  const float* hx = (const float*)d_in[0];
  const float* cx = (const float*)d_in[1];
  const float* Wih = (const float*)d_in[2];
  const float* Whh = (const float*)d_in[3];
  const float* bih = (const float*)d_in[4];
  const float* bhh = (const float*)d_in[5];
  const float* Wfcin = (const float*)d_in[6];
  const float* bfcin = (const float*)d_in[7];
  const float* Wfcout = (const float*)d_in[8];
  const float* bfcout = (const float*)d_in[9];
  const float* Wspan = (const float*)d_in[10];
  const float* bspan = (const float*)d_in[11];
  float* out = (float*)d_out;

  char* ws = (char*)d_ws;
  ushort_t* Wg = (ushort_t*)(ws);                // 4096*1536*2 = 12582912
  ushort_t* Wfc = (ushort_t*)(ws + 12582912);    // 512*1024*2  =  1048576
  float* bg = (float*)(ws + 13631488);           // 4096*4      =    16384
  ushort_t* XA = (ushort_t*)(ws + 13647872);     // 12582912
  ushort_t* XB = (ushort_t*)(ws + 26230784);     // 12582912
  float* cbuf = (float*)(ws + 38813696);         // 16777216 -> total 55590912 B

  prep_gates_w<<<(BSZ * XLD) / 256, 256, 0, stream>>>(Wih, Whh, bih, bhh, Wg, bg);
  prep_fcin_w<<<(INPD * HID) / 256, 256, 0, stream>>>(Wfcin, Wfc);
  init_kernel<<<(BSZ * HID) / 256, 256, 0, stream>>>(hx, cx, XA, cbuf);
  span_kernel<<<(BSZ * NSPAN) / 256, 256, 0, stream>>>(hx, Wspan, bspan, out);

  for (int t = 0; t < NDAYS; ++t) {
    ushort_t* Xin = (t & 1) ? XB : XA;
    ushort_t* Xout = (t & 1) ? XA : XB;
    gemm_kernel<0><<<dim3(32, 32), 256, 0, stream>>>(Xin, XLD, Wg, XLD, XLD, bg, cbuf, Xout);
    fcout_kernel<<<BSZ / 4, 256, 0, stream>>>(Xout, Wfcout, bfcout, out + BSZ * NSPAN, t);
    if (t < NDAYS - 1)
      gemm_kernel<1><<<dim3(32, 4), 256, 0, stream>>>(Xout + INPD, XLD, Wfc, HID, HID, bfcin,
                                                      nullptr, Xout);
  }
}